// Round 10
// baseline (187.597 us; speedup 1.0000x reference)
//
#include <hip/hip_runtime.h>
#include <hip/hip_bf16.h>
#include <cstdint>
#include <cstddef>

#define NN     50000
#define NE     800000
#define FIN    128
#define CAP    64       // per-node bucket capacity; P(Poisson(16)>64) ~ 5e-19
#define NBIN   784      // bins of 64 dst nodes: bin = dst>>6
#define CAPBIN 1280     // slots per bin segment; Poisson(1024)+6sigma ~ 1216
#define SB     157      // scatter blocks (pinned)
#define SCT    1024     // scatter/prep block threads (pinned, R13 win)
#define EPT    5        // edges per thread (157*1024*5 = 803840 >= NE)
#define PREPB  786      // prep blocks of 1024 thr x 8 floats (786*8192 >= 6432768)
#define NAB    782      // fused agg+gemm blocks: one per 64-node bin (782*64 >= NN)

using bf16x8 = __attribute__((ext_vector_type(8))) short;
using f32x4  = __attribute__((ext_vector_type(4))) float;
using f32x2  = __attribute__((ext_vector_type(2))) float;

// ---- workspace layout ----
static const size_t OFF_CUR  = 0;          // int[784]  bincursor (final = bin counts)
static const size_t OFF_PART = 800;        // int[784*1280 = 1,003,520]
static const size_t S_HB  = 2008640;       // bf16[6,400,000]
static const size_t S_HNB = 8408640;       // (unused after fusion; layout kept)
static const size_t S_WB  = 14808640;      // bf16[32,768]
static const size_t S_HF8 = 14841408;      // fp8 e4m3 rows as 3,200,000 shorts

__device__ __forceinline__ unsigned f2bf(float f) {
    unsigned u = __float_as_uint(f);
    return (u + 0x7FFFu + ((u >> 16) & 1u)) >> 16;   // RNE
}

// ---- K1: fused scatter (blocks 0..SB-1) + prep (rest) — R2-best exact ----
__global__ __launch_bounds__(SCT) void k_ps(
    const float* __restrict__ h, const float* __restrict__ W,
    unsigned* __restrict__ hB, unsigned* __restrict__ WB,
    uint2* __restrict__ hF8,
    const int* __restrict__ src, const int* __restrict__ dst,
    int* __restrict__ bincursor, int* __restrict__ part)
{
    __shared__ int lcur[NBIN];
    __shared__ int lofs[NBIN];
    __shared__ int gbase[NBIN];
    __shared__ int wsum[16];
    __shared__ int ebuf[EPT * SCT];
    int blk = blockIdx.x, tid = threadIdx.x;

    if (blk >= SB) {
        int i = (blk - SB) * SCT + tid;
        size_t e = (size_t)i * 8;
        const float* s;
        unsigned* d;
        bool isH = (e < 6400000);
        if (isH) { s = h + e; d = hB + e / 2; }
        else if (e < 6400000 + 32768) { s = W + (e - 6400000); d = WB + (e - 6400000) / 2; }
        else return;
        float4 a = *(const float4*)s;
        float4 b = *(const float4*)(s + 4);
        uint4 o;
        o.x = f2bf(a.x) | (f2bf(a.y) << 16);
        o.y = f2bf(a.z) | (f2bf(a.w) << 16);
        o.z = f2bf(b.x) | (f2bf(b.y) << 16);
        o.w = f2bf(b.z) | (f2bf(b.w) << 16);
        *(uint4*)d = o;
        if (isH) {
            int w0 = __builtin_amdgcn_cvt_pk_fp8_f32(a.x, a.y, 0, false);
            w0     = __builtin_amdgcn_cvt_pk_fp8_f32(a.z, a.w, w0, true);
            int w1 = __builtin_amdgcn_cvt_pk_fp8_f32(b.x, b.y, 0, false);
            w1     = __builtin_amdgcn_cvt_pk_fp8_f32(b.z, b.w, w1, true);
            hF8[e / 8] = make_uint2((unsigned)w0, (unsigned)w1);
        }
        return;
    }

    int b = blk;
    if (tid < NBIN) lcur[tid] = 0;
    __syncthreads();
    int e0 = b * (EPT * SCT);
    int pk[EPT], rk[EPT];
#pragma unroll
    for (int k = 0; k < EPT; ++k) {
        int e = e0 + k * SCT + tid;
        if (e < NE) {
            int d = dst[e];
            int s = src[e];
            int bin = d >> 6;
            pk[k] = s | ((d & 63) << 16) | (bin << 22);
            rk[k] = atomicAdd(&lcur[bin], 1);
        } else {
            pk[k] = -1;
        }
    }
    __syncthreads();

    int lane = tid & 63, wid = tid >> 6;
    int c = (tid < NBIN) ? lcur[tid] : 0;
    int v = c;
#pragma unroll
    for (int dd = 1; dd < 64; dd <<= 1) {
        int n = __shfl_up(v, dd);
        if (lane >= dd) v += n;
    }
    if (lane == 63) wsum[wid] = v;
    __syncthreads();
    if (wid == 0) {
        int s16 = (lane < 16) ? wsum[lane] : 0;
        int wv = s16;
#pragma unroll
        for (int dd = 1; dd < 16; dd <<= 1) {
            int n = __shfl_up(wv, dd);
            if (lane >= dd) wv += n;
        }
        if (lane < 16) wsum[lane] = wv - s16;
    }
    __syncthreads();
    if (tid < NBIN) {
        lofs[tid]  = v - c + wsum[wid];
        gbase[tid] = c ? atomicAdd(&bincursor[tid], c) : 0;
    }
    __syncthreads();

#pragma unroll
    for (int k = 0; k < EPT; ++k) {
        if (pk[k] != -1) {
            int bin = ((unsigned)pk[k]) >> 22;
            ebuf[lofs[bin] + rk[k]] = pk[k];
        }
    }
    __syncthreads();

    int total = min(NE - e0, EPT * SCT);
    for (int i = tid; i < total; i += SCT) {
        int e = ebuf[i];
        int bin = ((unsigned)e) >> 22;
        int g = gbase[bin] + (i - lofs[bin]);
        if (g < CAPBIN)
            part[bin * CAPBIN + g] = e & 0x3FFFFF;
    }
}

__device__ __forceinline__ f32x2 fp8lo(unsigned u) {
    return __builtin_amdgcn_cvt_pk_f32_fp8((int)u, false);
}
__device__ __forceinline__ f32x2 fp8hi(unsigned u) {
    return __builtin_amdgcn_cvt_pk_f32_fp8((int)u, true);
}

// ---- K2 (fused agg+gemm): one block per 64-node bin ----
// Dependency is bin-local (gemm rows 64b..64b+63 need agg of bin b only),
// so no grid sync is needed.  hN tile lives in LDS (never in HBM).
// LDS = WL 32KB + hNL 16KB + bucket 2KB + ldeg -> 50.3KB -> 3 blocks/CU.
// Agg inner loops and MFMA sequence are R2-exact -> bit-identical output.
__global__ __launch_bounds__(256) void k_aggemm(
    const int* __restrict__ part,
    const int* __restrict__ bincursor,
    const unsigned* __restrict__ hF8u,
    const short* __restrict__ hB,
    const short* __restrict__ WB,
    const float* __restrict__ bias,
    float* __restrict__ out)
{
    __shared__ short WL[16384];                    // 32 KB (j-half staged, reused)
    __shared__ short hNL[64 * 128];                // 16 KB, swizzled 16-chunk
    __shared__ unsigned short bucketL[16 * CAP];   // 2 KB
    __shared__ int ldeg[16];

    const int bin = blockIdx.x, tid = threadIdx.x;
    const int wave = tid >> 6, lane = tid & 63;
    const int halfid = lane >> 5;
    const int l32 = lane & 31;

    const int cnt = min(bincursor[bin], CAPBIN);
    const int* pj = part + bin * CAPBIN;

    // ---- agg phase: 4 subs x 16 nodes -> hNL rows 0..63 ----
    for (int sub = 0; sub < 4; ++sub) {
        if (tid < 16) ldeg[tid] = 0;
        __syncthreads();
        for (int i = tid; i < cnt; i += 256) {
            int v = pj[i];
            int local = (v >> 16) & 63;
            if ((local >> 4) == sub) {
                int l16 = local & 15;
                int slot = atomicAdd(&ldeg[l16], 1);
                if (slot < CAP) bucketL[l16 * CAP + slot] = (unsigned short)v;
            }
        }
        __syncthreads();
#pragma unroll
        for (int t = 0; t < 4; ++t) {
            int l16 = wave * 4 + t;
            int row = (sub << 4) + l16;      // local node 0..63
            // nodes >= NN: ldeg==0 -> zeros written (keeps hNL fully defined)
            int d = ldeg[l16];
            int c2 = min(d, CAP);
            const unsigned short* bp = &bucketL[l16 * CAP];
            float a0 = 0.f, a1 = 0.f, a2 = 0.f, a3 = 0.f;
            int i = 0;
            for (; i + 16 <= c2; i += 16) {
                unsigned uu[8];
#pragma unroll
                for (int j = 0; j < 8; ++j)
                    uu[j] = hF8u[(size_t)bp[i + 2 * j + halfid] * 32 + l32];
#pragma unroll
                for (int j = 0; j < 8; ++j) {
                    f32x2 lo = fp8lo(uu[j]);
                    f32x2 hi = fp8hi(uu[j]);
                    a0 += lo[0]; a1 += lo[1]; a2 += hi[0]; a3 += hi[1];
                }
            }
            for (; i < c2; i += 2) {
                int e = i + halfid;
                unsigned u = 0;
                if (e < c2) u = hF8u[(size_t)bp[e] * 32 + l32];
                f32x2 lo = fp8lo(u);
                f32x2 hi = fp8hi(u);
                a0 += lo[0]; a1 += lo[1]; a2 += hi[0]; a3 += hi[1];
            }
            a0 += __shfl_xor(a0, 32);
            a1 += __shfl_xor(a1, 32);
            a2 += __shfl_xor(a2, 32);
            a3 += __shfl_xor(a3, 32);
            if (halfid == 0) {
                float inv = 1.0f / fmaxf((float)d, 1.0f);
                unsigned p0 = f2bf(a0 * inv) | (f2bf(a1 * inv) << 16);
                unsigned p1 = f2bf(a2 * inv) | (f2bf(a3 * inv) << 16);
                int c  = l32 >> 1;               // 8-short chunk 0..15
                int cs = (c + row) & 15;         // swizzle matches gemm read
                *(uint2*)(&hNL[row * 128 + cs * 8 + (l32 & 1) * 4]) =
                    make_uint2(p0, p1);
            }
        }
        __syncthreads();
    }

    // ---- gemm phase: out[64 x 128] = [hB | hNL] @ W^T + b, j-half loop ----
    const int q    = lane >> 4;
    const int ln   = lane & 15;
    const int mrow = wave * 16 + ln;     // local A-row 0..63
    int node = bin * 64 + mrow;
    int nodec = (node < NN) ? node : NN - 1;   // safe hB pointer (rows guarded)

    for (int jh = 0; jh < 2; ++jh) {
        const int jbase = jh * 64;
        __syncthreads();   // previous WL consumers done (and hNL writes visible)
        for (int g = tid; g < 2048; g += 256) {
            int row = g >> 5;
            int c   = g & 31;
            int cs  = (c + row) & 31;
            bf16x8 v = *(const bf16x8*)(WB + (size_t)(jbase + row) * 256 + c * 8);
            *(bf16x8*)(&WL[row * 256 + cs * 8]) = v;
        }
        __syncthreads();

        f32x4 acc[4];
#pragma unroll
        for (int t = 0; t < 4; ++t) acc[t] = (f32x4){0.f, 0.f, 0.f, 0.f};

#pragma unroll
        for (int k0 = 0; k0 < 8; ++k0) {
            int ck = k0 * 4 + q;
            bf16x8 afr;
            if (k0 < 4) {
                afr = *(const bf16x8*)(hB + (size_t)nodec * 128 + ck * 8);
            } else {
                int ckn = ck - 16;               // 0..15
                int csn = (ckn + mrow) & 15;
                afr = *(const bf16x8*)(&hNL[mrow * 128 + csn * 8]);
            }
#pragma unroll
            for (int t = 0; t < 4; ++t) {
                int row = t * 16 + ln;
                int cs  = (ck + row) & 31;
                bf16x8 bfr = *(const bf16x8*)(&WL[row * 256 + cs * 8]);
                acc[t] = __builtin_amdgcn_mfma_f32_16x16x32_bf16(afr, bfr, acc[t], 0, 0, 0);
            }
        }

#pragma unroll
        for (int t = 0; t < 4; ++t) {
            int j = jbase + t * 16 + ln;
            float bv = bias[j];
#pragma unroll
            for (int r = 0; r < 4; ++r) {
                int m = bin * 64 + wave * 16 + q * 4 + r;
                if (m < NN)
                    out[(size_t)m * FIN + j] = acc[t][r] + bv;
            }
        }
    }
}

extern "C" void kernel_launch(void* const* d_in, const int* in_sizes, int n_in,
                              void* d_out, int out_size, void* d_ws, size_t ws_size,
                              hipStream_t stream) {
    const float* h   = (const float*)d_in[0];
    const int*   src = (const int*)d_in[1];
    const int*   dst = (const int*)d_in[2];
    const float* W   = (const float*)d_in[3];
    const float* b   = (const float*)d_in[4];
    float* out = (float*)d_out;

    int*   wsI = (int*)d_ws;
    short* wsS = (short*)d_ws;

    int* bincursor = wsI + OFF_CUR;
    int* part      = wsI + OFF_PART;
    short* hB      = wsS + S_HB;
    short* WB      = wsS + S_WB;
    const unsigned* hF8u = (const unsigned*)(wsS + S_HF8);

    hipMemsetAsync(bincursor, 0, NBIN * sizeof(int), stream);
    k_ps     <<<SB + PREPB, SCT, 0, stream>>>(
        h, W, (unsigned*)hB, (unsigned*)WB, (uint2*)(wsS + S_HF8),
        src, dst, bincursor, part);
    k_aggemm <<<NAB, 256, 0, stream>>>(part, bincursor, hF8u, hB, WB, b, out);
}

// Round 11
// 155.472 us; speedup vs baseline: 1.2066x; 1.2066x over previous
//
#include <hip/hip_runtime.h>
#include <hip/hip_bf16.h>
#include <cstdint>
#include <cstddef>

#define NN     50000
#define NE     800000
#define FIN    128
#define CAP    64       // per-node bucket capacity; P(Poisson(16)>64) ~ 5e-19
#define NBIN   784      // bins of 64 dst nodes: bin = dst>>6
#define CAPBIN 1280     // slots per bin segment; Poisson(1024)+6sigma ~ 1216
#define SB     157      // scatter blocks (pinned)
#define SCT    1024     // scatter/prep block threads (pinned, R13 win)
#define EPT    5        // edges per thread (157*1024*5 = 803840 >= NE)
#define PREPB  786      // prep blocks of 1024 thr x 8 floats (786*8192 >= 6432768)
#define NAB    782      // fused agg+gemm blocks: one per 64-node bin

using bf16x8 = __attribute__((ext_vector_type(8))) short;
using f32x4  = __attribute__((ext_vector_type(4))) float;
using f32x2  = __attribute__((ext_vector_type(2))) float;

// ---- workspace layout ----
static const size_t OFF_CUR  = 0;          // int[784]  bincursor (final = bin counts)
static const size_t OFF_PART = 800;        // int[784*1280 = 1,003,520]
static const size_t S_HB  = 2008640;       // bf16[6,400,000]
static const size_t S_WB  = 14808640;      // bf16[32,768]
static const size_t S_HF8 = 14841408;      // fp8 e4m3 rows as 3,200,000 shorts

__device__ __forceinline__ unsigned f2bf(float f) {
    unsigned u = __float_as_uint(f);
    return (u + 0x7FFFu + ((u >> 16) & 1u)) >> 16;   // RNE
}

// ---- K1: fused scatter (blocks 0..SB-1) + prep (rest) — R2-best exact ----
__global__ __launch_bounds__(SCT) void k_ps(
    const float* __restrict__ h, const float* __restrict__ W,
    unsigned* __restrict__ hB, unsigned* __restrict__ WB,
    uint2* __restrict__ hF8,
    const int* __restrict__ src, const int* __restrict__ dst,
    int* __restrict__ bincursor, int* __restrict__ part)
{
    __shared__ int lcur[NBIN];
    __shared__ int lofs[NBIN];
    __shared__ int gbase[NBIN];
    __shared__ int wsum[16];
    __shared__ int ebuf[EPT * SCT];
    int blk = blockIdx.x, tid = threadIdx.x;

    if (blk >= SB) {
        int i = (blk - SB) * SCT + tid;
        size_t e = (size_t)i * 8;
        const float* s;
        unsigned* d;
        bool isH = (e < 6400000);
        if (isH) { s = h + e; d = hB + e / 2; }
        else if (e < 6400000 + 32768) { s = W + (e - 6400000); d = WB + (e - 6400000) / 2; }
        else return;
        float4 a = *(const float4*)s;
        float4 b = *(const float4*)(s + 4);
        uint4 o;
        o.x = f2bf(a.x) | (f2bf(a.y) << 16);
        o.y = f2bf(a.z) | (f2bf(a.w) << 16);
        o.z = f2bf(b.x) | (f2bf(b.y) << 16);
        o.w = f2bf(b.z) | (f2bf(b.w) << 16);
        *(uint4*)d = o;
        if (isH) {
            int w0 = __builtin_amdgcn_cvt_pk_fp8_f32(a.x, a.y, 0, false);
            w0     = __builtin_amdgcn_cvt_pk_fp8_f32(a.z, a.w, w0, true);
            int w1 = __builtin_amdgcn_cvt_pk_fp8_f32(b.x, b.y, 0, false);
            w1     = __builtin_amdgcn_cvt_pk_fp8_f32(b.z, b.w, w1, true);
            hF8[e / 8] = make_uint2((unsigned)w0, (unsigned)w1);
        }
        return;
    }

    int b = blk;
    if (tid < NBIN) lcur[tid] = 0;
    __syncthreads();
    int e0 = b * (EPT * SCT);
    int pk[EPT], rk[EPT];
#pragma unroll
    for (int k = 0; k < EPT; ++k) {
        int e = e0 + k * SCT + tid;
        if (e < NE) {
            int d = dst[e];
            int s = src[e];
            int bin = d >> 6;
            pk[k] = s | ((d & 63) << 16) | (bin << 22);
            rk[k] = atomicAdd(&lcur[bin], 1);
        } else {
            pk[k] = -1;
        }
    }
    __syncthreads();

    int lane = tid & 63, wid = tid >> 6;
    int c = (tid < NBIN) ? lcur[tid] : 0;
    int v = c;
#pragma unroll
    for (int dd = 1; dd < 64; dd <<= 1) {
        int n = __shfl_up(v, dd);
        if (lane >= dd) v += n;
    }
    if (lane == 63) wsum[wid] = v;
    __syncthreads();
    if (wid == 0) {
        int s16 = (lane < 16) ? wsum[lane] : 0;
        int wv = s16;
#pragma unroll
        for (int dd = 1; dd < 16; dd <<= 1) {
            int n = __shfl_up(wv, dd);
            if (lane >= dd) wv += n;
        }
        if (lane < 16) wsum[lane] = wv - s16;
    }
    __syncthreads();
    if (tid < NBIN) {
        lofs[tid]  = v - c + wsum[wid];
        gbase[tid] = c ? atomicAdd(&bincursor[tid], c) : 0;
    }
    __syncthreads();

#pragma unroll
    for (int k = 0; k < EPT; ++k) {
        if (pk[k] != -1) {
            int bin = ((unsigned)pk[k]) >> 22;
            ebuf[lofs[bin] + rk[k]] = pk[k];
        }
    }
    __syncthreads();

    int total = min(NE - e0, EPT * SCT);
    for (int i = tid; i < total; i += SCT) {
        int e = ebuf[i];
        int bin = ((unsigned)e) >> 22;
        int g = gbase[bin] + (i - lofs[bin]);
        if (g < CAPBIN)
            part[bin * CAPBIN + g] = e & 0x3FFFFF;
    }
}

__device__ __forceinline__ f32x2 fp8lo(unsigned u) {
    return __builtin_amdgcn_cvt_pk_f32_fp8((int)u, false);
}
__device__ __forceinline__ f32x2 fp8hi(unsigned u) {
    return __builtin_amdgcn_cvt_pk_f32_fp8((int)u, true);
}

// ---- K2 (fused agg+gemm v3): 1024-thr block per bin, occupancy-parity ----
// LDS = bucketL 8KB + hNL 16KB + ldeg 256B ~= 24.8KB; __launch_bounds__(1024,8)
// caps VGPR<=64 -> 2 blocks/CU = 32 waves/CU (max) for the latency-bound gather.
// W is read from global (L1/L2-resident, 64KB) -> no WL staging, LDS stays small.
// Gather inner loop + MFMA per-output chain are R2/R10-exact -> absmax unchanged.
__global__ __launch_bounds__(1024, 8) void k_aggemm(
    const int* __restrict__ part,
    const int* __restrict__ bincursor,
    const unsigned* __restrict__ hF8u,
    const short* __restrict__ hB,
    const short* __restrict__ WB,
    const float* __restrict__ bias,
    float* __restrict__ out)
{
    __shared__ unsigned short bucketL[64 * CAP];   // 8 KB
    __shared__ short hNL[64 * 128];                // 16 KB, swizzled 16-chunk
    __shared__ int ldeg[64];

    const int bin = blockIdx.x, tid = threadIdx.x;
    const int wid = tid >> 6, lane = tid & 63;
    const int halfid = lane >> 5;
    const int l32 = lane & 31;

    if (tid < 64) ldeg[tid] = 0;
    __syncthreads();

    // ---- bucket: single scan of the bin segment, all 64 locals at once ----
    const int cnt = min(bincursor[bin], CAPBIN);
    const int* pj = part + bin * CAPBIN;
    for (int i = tid; i < cnt; i += 1024) {
        int v = pj[i];
        int local = (v >> 16) & 63;
        int slot = atomicAdd(&ldeg[local], 1);
        if (slot < CAP) bucketL[local * CAP + slot] = (unsigned short)v;
    }
    __syncthreads();

    // ---- gather-mean: 16 waves x 4 nodes, R2-exact inner loop ----
#pragma unroll
    for (int t = 0; t < 4; ++t) {
        int l6 = wid * 4 + t;            // local node 0..63 (hNL row)
        int d = ldeg[l6];
        int c2 = min(d, CAP);
        const unsigned short* bp = &bucketL[l6 * CAP];
        float a0 = 0.f, a1 = 0.f, a2 = 0.f, a3 = 0.f;
        int i = 0;
        for (; i + 16 <= c2; i += 16) {
            unsigned uu[8];
#pragma unroll
            for (int j = 0; j < 8; ++j)
                uu[j] = hF8u[(size_t)bp[i + 2 * j + halfid] * 32 + l32];
#pragma unroll
            for (int j = 0; j < 8; ++j) {
                f32x2 lo = fp8lo(uu[j]);
                f32x2 hi = fp8hi(uu[j]);
                a0 += lo[0]; a1 += lo[1]; a2 += hi[0]; a3 += hi[1];
            }
        }
        for (; i < c2; i += 2) {
            int e = i + halfid;
            unsigned u = 0;
            if (e < c2) u = hF8u[(size_t)bp[e] * 32 + l32];
            f32x2 lo = fp8lo(u);
            f32x2 hi = fp8hi(u);
            a0 += lo[0]; a1 += lo[1]; a2 += hi[0]; a3 += hi[1];
        }
        a0 += __shfl_xor(a0, 32);
        a1 += __shfl_xor(a1, 32);
        a2 += __shfl_xor(a2, 32);
        a3 += __shfl_xor(a3, 32);
        if (halfid == 0) {
            // nodes >= NN have ldeg==0 -> zeros (hNL fully defined)
            float inv = 1.0f / fmaxf((float)d, 1.0f);
            unsigned p0 = f2bf(a0 * inv) | (f2bf(a1 * inv) << 16);
            unsigned p1 = f2bf(a2 * inv) | (f2bf(a3 * inv) << 16);
            int c  = l32 >> 1;               // 8-short chunk 0..15
            int cs = (c + l6) & 15;          // swizzle matches gemm read
            *(uint2*)(&hNL[l6 * 128 + cs * 8 + (l32 & 1) * 4]) = make_uint2(p0, p1);
        }
    }
    __syncthreads();

    // ---- gemm: 16 waves = 4 m-tiles x 4 j-quarters; W from global (L2) ----
    const int q    = lane >> 4;
    const int ln   = lane & 15;
    const int mt   = wid & 3;            // m-tile 0..3
    const int jq   = wid >> 2;           // j-quarter 0..3 (32 cols each)
    const int mrow = mt * 16 + ln;       // local A-row 0..63
    int node = bin * 64 + mrow;
    int nodec = (node < NN) ? node : NN - 1;

    f32x4 acc[2];
#pragma unroll
    for (int t = 0; t < 2; ++t) acc[t] = (f32x4){0.f, 0.f, 0.f, 0.f};

#pragma unroll
    for (int k0 = 0; k0 < 8; ++k0) {
        int ck = k0 * 4 + q;
        bf16x8 afr;
        if (k0 < 4) {
            afr = *(const bf16x8*)(hB + (size_t)nodec * 128 + ck * 8);
        } else {
            int ckn = ck - 16;               // 0..15
            int csn = (ckn + mrow) & 15;
            afr = *(const bf16x8*)(&hNL[mrow * 128 + csn * 8]);
        }
#pragma unroll
        for (int t = 0; t < 2; ++t) {
            int j = jq * 32 + t * 16 + ln;   // output column 0..127
            bf16x8 bfr = *(const bf16x8*)(WB + (size_t)j * 256 + ck * 8);
            acc[t] = __builtin_amdgcn_mfma_f32_16x16x32_bf16(afr, bfr, acc[t], 0, 0, 0);
        }
    }

#pragma unroll
    for (int t = 0; t < 2; ++t) {
        int j = jq * 32 + t * 16 + ln;
        float bv = bias[j];
#pragma unroll
        for (int r = 0; r < 4; ++r) {
            int m = bin * 64 + mt * 16 + q * 4 + r;
            if (m < NN)
                out[(size_t)m * FIN + j] = acc[t][r] + bv;
        }
    }
}

extern "C" void kernel_launch(void* const* d_in, const int* in_sizes, int n_in,
                              void* d_out, int out_size, void* d_ws, size_t ws_size,
                              hipStream_t stream) {
    const float* h   = (const float*)d_in[0];
    const int*   src = (const int*)d_in[1];
    const int*   dst = (const int*)d_in[2];
    const float* W   = (const float*)d_in[3];
    const float* b   = (const float*)d_in[4];
    float* out = (float*)d_out;

    int*   wsI = (int*)d_ws;
    short* wsS = (short*)d_ws;

    int* bincursor = wsI + OFF_CUR;
    int* part      = wsI + OFF_PART;
    short* hB      = wsS + S_HB;
    short* WB      = wsS + S_WB;
    const unsigned* hF8u = (const unsigned*)(wsS + S_HF8);

    hipMemsetAsync(bincursor, 0, NBIN * sizeof(int), stream);
    k_ps     <<<SB + PREPB, SCT, 0, stream>>>(
        h, W, (unsigned*)hB, (unsigned*)WB, (uint2*)(wsS + S_HF8),
        src, dst, bincursor, part);
    k_aggemm <<<NAB, 1024, 0, stream>>>(part, bincursor, hF8u, hB, WB, b, out);
}

// Round 12
// 150.715 us; speedup vs baseline: 1.2447x; 1.0316x over previous
//
#include <hip/hip_runtime.h>
#include <hip/hip_bf16.h>
#include <cstdint>
#include <cstddef>

#define NN     50000
#define NE     800000
#define FIN    128
#define CAP    64       // per-node bucket capacity; P(Poisson(16)>64) ~ 5e-19
#define NBIN   784      // bins of 64 dst nodes: bin = dst>>6
#define SB     157      // scatter blocks (pinned)
#define SCT    1024     // scatter/prep block threads (pinned, R13 win)
#define EPT    5        // edges per thread (157*1024*5 = 803840 >= NE)
#define PREPB  786      // prep blocks of 1024 thr x 8 floats (786*8192 >= 6432768)
#define SEG    32       // per-(bin,block) segment slots; Poisson(6.5)+10sigma

using bf16x8 = __attribute__((ext_vector_type(8))) short;
using f32x4  = __attribute__((ext_vector_type(4))) float;
using f32x2  = __attribute__((ext_vector_type(2))) float;

// ---- workspace layout ----
// shorts (from (short*)d_ws) — unchanged region, ends at byte ~36.1 MB
static const size_t S_HB  = 2008640;       // bf16[6,400,000]
static const size_t S_HNB = 8408640;       // bf16[6,400,000]
static const size_t S_WB  = 14808640;      // bf16[32,768]
static const size_t S_HF8 = 14841408;      // fp8 e4m3 rows as 3,200,000 shorts
// ints (from (int*)d_ws) — cursor-free scatter state, above 40 MB
static const size_t OFF_PART2 = 10485760;  // int[784*157*32 = 3,938,816] @40MB
static const size_t OFF_CNT2  = 15204352;  // int[157*784 = 123,088]      @58MB
// no memset needed: every cnt2/part2 cell is written unconditionally

__device__ __forceinline__ unsigned f2bf(float f) {
    unsigned u = __float_as_uint(f);
    return (u + 0x7FFFu + ((u >> 16) & 1u)) >> 16;   // RNE
}

// ---- K1: fused scatter (blocks 0..SB-1) + prep (rest) ----
// R12 change: cursor-free scatter.  Block b writes its bin-j entries to the
// fixed segment part2[(j*157+b)*SEG .. +SEG) and the count to cnt2[b*784+j].
// No global bincursor, no atomics, NO PRE-ZERO -> memset dispatch eliminated.
// Ranks rk and block-local order identical to R2 (bit-neutral: fp8 sums exact).
__global__ __launch_bounds__(SCT) void k_ps(
    const float* __restrict__ h, const float* __restrict__ W,
    unsigned* __restrict__ hB, unsigned* __restrict__ WB,
    uint2* __restrict__ hF8,
    const int* __restrict__ src, const int* __restrict__ dst,
    int* __restrict__ part2, int* __restrict__ cnt2)
{
    __shared__ int lcur[NBIN];
    __shared__ int lofs[NBIN];
    __shared__ int wsum[16];
    __shared__ int ebuf[EPT * SCT];
    int blk = blockIdx.x, tid = threadIdx.x;

    if (blk >= SB) {
        int i = (blk - SB) * SCT + tid;
        size_t e = (size_t)i * 8;
        const float* s;
        unsigned* d;
        bool isH = (e < 6400000);
        if (isH) { s = h + e; d = hB + e / 2; }
        else if (e < 6400000 + 32768) { s = W + (e - 6400000); d = WB + (e - 6400000) / 2; }
        else return;
        float4 a = *(const float4*)s;
        float4 b = *(const float4*)(s + 4);
        uint4 o;
        o.x = f2bf(a.x) | (f2bf(a.y) << 16);
        o.y = f2bf(a.z) | (f2bf(a.w) << 16);
        o.z = f2bf(b.x) | (f2bf(b.y) << 16);
        o.w = f2bf(b.z) | (f2bf(b.w) << 16);
        *(uint4*)d = o;
        if (isH) {
            int w0 = __builtin_amdgcn_cvt_pk_fp8_f32(a.x, a.y, 0, false);
            w0     = __builtin_amdgcn_cvt_pk_fp8_f32(a.z, a.w, w0, true);
            int w1 = __builtin_amdgcn_cvt_pk_fp8_f32(b.x, b.y, 0, false);
            w1     = __builtin_amdgcn_cvt_pk_fp8_f32(b.z, b.w, w1, true);
            hF8[e / 8] = make_uint2((unsigned)w0, (unsigned)w1);
        }
        return;
    }

    // ---- phase 1: per-block bin counts + ranks (R2 exact) ----
    int b = blk;
    if (tid < NBIN) lcur[tid] = 0;
    __syncthreads();
    int e0 = b * (EPT * SCT);
    int pk[EPT], rk[EPT];
#pragma unroll
    for (int k = 0; k < EPT; ++k) {
        int e = e0 + k * SCT + tid;
        if (e < NE) {
            int d = dst[e];
            int s = src[e];
            int bin = d >> 6;
            pk[k] = s | ((d & 63) << 16) | (bin << 22);
            rk[k] = atomicAdd(&lcur[bin], 1);
        } else {
            pk[k] = -1;
        }
    }
    __syncthreads();

    // ---- phase 2: block-local exclusive prefix (for LDS sort) + cnt2 write ----
    int lane = tid & 63, wid = tid >> 6;
    int c = (tid < NBIN) ? lcur[tid] : 0;
    int v = c;
#pragma unroll
    for (int dd = 1; dd < 64; dd <<= 1) {
        int n = __shfl_up(v, dd);
        if (lane >= dd) v += n;
    }
    if (lane == 63) wsum[wid] = v;
    __syncthreads();
    if (wid == 0) {
        int s16 = (lane < 16) ? wsum[lane] : 0;
        int wv = s16;
#pragma unroll
        for (int dd = 1; dd < 16; dd <<= 1) {
            int n = __shfl_up(wv, dd);
            if (lane >= dd) wv += n;
        }
        if (lane < 16) wsum[lane] = wv - s16;
    }
    __syncthreads();
    if (tid < NBIN) {
        lofs[tid] = v - c + wsum[wid];
        cnt2[b * NBIN + tid] = min(c, SEG);   // coalesced, unconditional
    }
    __syncthreads();

    // ---- phase 3: LDS counting-sort scatter ----
#pragma unroll
    for (int k = 0; k < EPT; ++k) {
        if (pk[k] != -1) {
            int bin = ((unsigned)pk[k]) >> 22;
            ebuf[lofs[bin] + rk[k]] = pk[k];
        }
    }
    __syncthreads();

    // ---- phase 4: per-bin-run writes into fixed segments ----
    int total = min(NE - e0, EPT * SCT);
    for (int i = tid; i < total; i += SCT) {
        int e = ebuf[i];
        int bin = ((unsigned)e) >> 22;
        int r = i - lofs[bin];               // rank within this block's bin run
        if (r < SEG)
            part2[((size_t)bin * SB + b) * SEG + r] = e & 0x3FFFFF;
    }
}

__device__ __forceinline__ f32x2 fp8lo(unsigned u) {
    return __builtin_amdgcn_cvt_pk_f32_fp8((int)u, false);
}
__device__ __forceinline__ f32x2 fp8hi(unsigned u) {
    return __builtin_amdgcn_cvt_pk_f32_fp8((int)u, true);
}

// ---- K2: per-quarter-bin LDS bucket + paired gather-mean (R2 inner loop) ----
// R12 change: scan the bin's 157 fixed segments (predicated by cnt2) instead
// of a dense cursor-run.  Bucket contents identical up to segment order.
__global__ __launch_bounds__(256) void k_aggbin(const int* __restrict__ part2,
                                                const int* __restrict__ cnt2,
                                                const unsigned* __restrict__ hF8u,
                                                unsigned* __restrict__ hNB2) {
    __shared__ int ldeg[16];
    __shared__ unsigned short bucketL[16 * CAP];   // 2 KB
    __shared__ int cblk[SB];
    int blk = blockIdx.x, tid = threadIdx.x;
    int bin = blk >> 2, sub = blk & 3;
    if (tid < 16) ldeg[tid] = 0;
    if (tid >= 64 && tid < 64 + SB) cblk[tid - 64] = cnt2[(tid - 64) * NBIN + bin];
    __syncthreads();
    const int* pj = part2 + (size_t)bin * SB * SEG;
    for (int i = tid; i < SB * SEG; i += 256) {
        int b = i >> 5;                  // SEG = 32
        int k = i & (SEG - 1);
        if (k < cblk[b]) {
            int v = pj[i];
            int local = (v >> 16) & 63;
            if ((local >> 4) == sub) {
                int l16 = local & 15;
                int slot = atomicAdd(&ldeg[l16], 1);
                if (slot < CAP) bucketL[l16 * CAP + slot] = (unsigned short)v;
            }
        }
    }
    __syncthreads();
    int wave = tid >> 6, lane = tid & 63;
    int halfid = lane >> 5;        // which edge of the pair
    int l32 = lane & 31;           // feature group: 4 fp8 feats 4*l32..+3
#pragma unroll
    for (int t = 0; t < 4; ++t) {
        int l16 = wave * 4 + t;
        int n = bin * 64 + (sub << 4) + l16;
        if (n >= NN) continue;
        int d = ldeg[l16];
        int c2 = min(d, CAP);
        const unsigned short* bp = &bucketL[l16 * CAP];
        float a0 = 0.f, a1 = 0.f, a2 = 0.f, a3 = 0.f;
        int i = 0;
        for (; i + 16 <= c2; i += 16) {
            unsigned uu[8];
#pragma unroll
            for (int j = 0; j < 8; ++j)
                uu[j] = hF8u[(size_t)bp[i + 2 * j + halfid] * 32 + l32];
#pragma unroll
            for (int j = 0; j < 8; ++j) {
                f32x2 lo = fp8lo(uu[j]);
                f32x2 hi = fp8hi(uu[j]);
                a0 += lo[0]; a1 += lo[1]; a2 += hi[0]; a3 += hi[1];
            }
        }
        for (; i < c2; i += 2) {
            int e = i + halfid;
            unsigned u = 0;
            if (e < c2) u = hF8u[(size_t)bp[e] * 32 + l32];
            f32x2 lo = fp8lo(u);
            f32x2 hi = fp8hi(u);
            a0 += lo[0]; a1 += lo[1]; a2 += hi[0]; a3 += hi[1];
        }
        a0 += __shfl_xor(a0, 32);
        a1 += __shfl_xor(a1, 32);
        a2 += __shfl_xor(a2, 32);
        a3 += __shfl_xor(a3, 32);
        if (halfid == 0) {
            float inv = 1.0f / fmaxf((float)d, 1.0f);
            unsigned p0 = f2bf(a0 * inv) | (f2bf(a1 * inv) << 16);
            unsigned p1 = f2bf(a2 * inv) | (f2bf(a3 * inv) << 16);
            *(uint2*)(hNB2 + (size_t)n * 64 + l32 * 2) = make_uint2(p0, p1);
        }
    }
}

// ---- K3: out = [hB | hNB] @ W^T + b via MFMA, LDS-staged W, j-split (R2 exact) ----
__global__ __launch_bounds__(256) void k_gemm(
    const short* __restrict__ hB, const short* __restrict__ hNB,
    const short* __restrict__ WB, const float* __restrict__ bias,
    float* __restrict__ out)
{
    __shared__ short WL[16384];   // 32 KB
    const int tid = threadIdx.x;
    const int jbase = blockIdx.y * 64;

    for (int g = tid; g < 2048; g += 256) {
        int row = g >> 5;          // 0..63
        int c   = g & 31;          // k-chunk
        int cs  = (c + row) & 31;  // swizzled
        bf16x8 v = *(const bf16x8*)(WB + (size_t)(jbase + row) * 256 + c * 8);
        *(bf16x8*)(&WL[row * 256 + cs * 8]) = v;
    }
    __syncthreads();

    const int wave = tid >> 6;
    const int lane = tid & 63;
    const int q    = lane >> 4;
    const int ln   = lane & 15;
    const int mbase = (blockIdx.x * 4 + wave) * 16;
    int node = mbase + ln;
    if (node >= NN) node = NN - 1;

    f32x4 acc[4];
#pragma unroll
    for (int t = 0; t < 4; ++t) acc[t] = (f32x4){0.f, 0.f, 0.f, 0.f};

#pragma unroll
    for (int k0 = 0; k0 < 8; ++k0) {
        int ck = k0 * 4 + q;
        const short* ap = (k0 < 4) ? (hB  + (size_t)node * 128 + ck * 8)
                                   : (hNB + (size_t)node * 128 + (ck - 16) * 8);
        bf16x8 afr = *(const bf16x8*)ap;
#pragma unroll
        for (int t = 0; t < 4; ++t) {
            int row = t * 16 + ln;
            int cs  = (ck + row) & 31;
            bf16x8 bfr = *(const bf16x8*)(&WL[row * 256 + cs * 8]);
            acc[t] = __builtin_amdgcn_mfma_f32_16x16x32_bf16(afr, bfr, acc[t], 0, 0, 0);
        }
    }

#pragma unroll
    for (int t = 0; t < 4; ++t) {
        float bv = bias[jbase + t * 16 + ln];
#pragma unroll
        for (int r = 0; r < 4; ++r) {
            int m = mbase + q * 4 + r;
            if (m < NN)
                out[(size_t)m * FIN + jbase + t * 16 + ln] = acc[t][r] + bv;
        }
    }
}

extern "C" void kernel_launch(void* const* d_in, const int* in_sizes, int n_in,
                              void* d_out, int out_size, void* d_ws, size_t ws_size,
                              hipStream_t stream) {
    const float* h   = (const float*)d_in[0];
    const int*   src = (const int*)d_in[1];
    const int*   dst = (const int*)d_in[2];
    const float* W   = (const float*)d_in[3];
    const float* b   = (const float*)d_in[4];
    float* out = (float*)d_out;

    int*   wsI = (int*)d_ws;
    short* wsS = (short*)d_ws;

    int* part2 = wsI + OFF_PART2;
    int* cnt2  = wsI + OFF_CNT2;
    short* hB  = wsS + S_HB;
    short* hNB = wsS + S_HNB;
    short* WB  = wsS + S_WB;
    const unsigned* hF8u = (const unsigned*)(wsS + S_HF8);

    // cursor-free pipeline: NO memset dispatch
    k_ps     <<<SB + PREPB, SCT, 0, stream>>>(
        h, W, (unsigned*)hB, (unsigned*)WB, (uint2*)(wsS + S_HF8),
        src, dst, part2, cnt2);
    k_aggbin <<<NBIN * 4, 256, 0, stream>>>(part2, cnt2, hF8u, (unsigned*)hNB);
    k_gemm   <<<dim3((NN + 63) / 64, 2), 256, 0, stream>>>(hB, hNB, WB, b, out);
}

// Round 13
// 138.413 us; speedup vs baseline: 1.3553x; 1.0889x over previous
//
#include <hip/hip_runtime.h>
#include <hip/hip_bf16.h>
#include <cstdint>
#include <cstddef>

#define NN     50000
#define NE     800000
#define FIN    128
#define CAP    64       // per-node bucket capacity; P(Poisson(16)>64) ~ 5e-19
#define NBIN   784      // bins of 64 dst nodes: bin = dst>>6
#define CAPBIN 1280     // slots per bin segment; Poisson(1024)+6sigma ~ 1216
#define SB     157      // scatter blocks (pinned)
#define SCT    1024     // scatter/prep block threads (pinned)
#define EPT    5        // edges per thread (157*1024*5 = 803840 >= NE)
#define PREPB  786      // prep blocks of 1024 thr x 8 floats (786*8192 >= 6432768)

using bf16x8 = __attribute__((ext_vector_type(8))) short;
using f32x4  = __attribute__((ext_vector_type(4))) float;
using f32x2  = __attribute__((ext_vector_type(2))) float;

// ---- workspace layout ----
static const size_t OFF_CUR  = 0;          // int[784]  bincursor (final = bin counts)
static const size_t OFF_PART = 800;        // int[784*1280 = 1,003,520]
static const size_t S_HB  = 2008640;       // bf16[6,400,000]
static const size_t S_HNB = 8408640;       // bf16[6,400,000]
static const size_t S_WB  = 14808640;      // bf16[32,768]
static const size_t S_HF8 = 14841408;      // fp8 e4m3 rows as 3,200,000 shorts
// end = 18,041,408 shorts = 36.1 MB

__device__ __forceinline__ unsigned f2bf(float f) {
    unsigned u = __float_as_uint(f);
    return (u + 0x7FFFu + ((u >> 16) & 1u)) >> 16;   // RNE
}

// ---- K1: fused scatter (blocks 0..SB-1) + prep (rest) — R2-best exact ----
// Scatter: block-local counting sort (LDS prefix-sum + LDS scatter) so part[]
// writes go out as coalesced per-bin runs.  part[] position = gbase + rank.
__global__ __launch_bounds__(SCT) void k_ps(
    const float* __restrict__ h, const float* __restrict__ W,
    unsigned* __restrict__ hB, unsigned* __restrict__ WB,
    uint2* __restrict__ hF8,
    const int* __restrict__ src, const int* __restrict__ dst,
    int* __restrict__ bincursor, int* __restrict__ part)
{
    __shared__ int lcur[NBIN];
    __shared__ int lofs[NBIN];      // block-local exclusive bin offsets
    __shared__ int gbase[NBIN];     // global base per bin (atomicAdd result)
    __shared__ int wsum[16];
    __shared__ int ebuf[EPT * SCT]; // 20 KB: entries sorted by bin
    int blk = blockIdx.x, tid = threadIdx.x;

    if (blk >= SB) {
        // ---- prep: convert h -> bf16 + fp8, W -> bf16; 8 floats/thread ----
        int i = (blk - SB) * SCT + tid;
        size_t e = (size_t)i * 8;
        const float* s;
        unsigned* d;
        bool isH = (e < 6400000);
        if (isH) { s = h + e; d = hB + e / 2; }
        else if (e < 6400000 + 32768) { s = W + (e - 6400000); d = WB + (e - 6400000) / 2; }
        else return;
        float4 a = *(const float4*)s;
        float4 b = *(const float4*)(s + 4);
        uint4 o;
        o.x = f2bf(a.x) | (f2bf(a.y) << 16);
        o.y = f2bf(a.z) | (f2bf(a.w) << 16);
        o.z = f2bf(b.x) | (f2bf(b.y) << 16);
        o.w = f2bf(b.z) | (f2bf(b.w) << 16);
        *(uint4*)d = o;
        if (isH) {
            int w0 = __builtin_amdgcn_cvt_pk_fp8_f32(a.x, a.y, 0, false);
            w0     = __builtin_amdgcn_cvt_pk_fp8_f32(a.z, a.w, w0, true);
            int w1 = __builtin_amdgcn_cvt_pk_fp8_f32(b.x, b.y, 0, false);
            w1     = __builtin_amdgcn_cvt_pk_fp8_f32(b.z, b.w, w1, true);
            hF8[e / 8] = make_uint2((unsigned)w0, (unsigned)w1);
        }
        return;
    }

    // ---- scatter phase 1: per-block bin counts + ranks ----
    int b = blk;
    if (tid < NBIN) lcur[tid] = 0;
    __syncthreads();
    int e0 = b * (EPT * SCT);
    int pk[EPT], rk[EPT];
#pragma unroll
    for (int k = 0; k < EPT; ++k) {
        int e = e0 + k * SCT + tid;
        if (e < NE) {
            int d = dst[e];
            int s = src[e];
            int bin = d >> 6;
            pk[k] = s | ((d & 63) << 16) | (bin << 22);   // s:16 | local:6 | bin:10
            rk[k] = atomicAdd(&lcur[bin], 1);
        } else {
            pk[k] = -1;
        }
    }
    __syncthreads();

    // ---- phase 2: exclusive prefix-sum over the 784 bin counts ----
    int lane = tid & 63, wid = tid >> 6;
    int c = (tid < NBIN) ? lcur[tid] : 0;
    int v = c;
#pragma unroll
    for (int dd = 1; dd < 64; dd <<= 1) {
        int n = __shfl_up(v, dd);
        if (lane >= dd) v += n;
    }
    if (lane == 63) wsum[wid] = v;
    __syncthreads();
    if (wid == 0) {
        int s16 = (lane < 16) ? wsum[lane] : 0;
        int wv = s16;
#pragma unroll
        for (int dd = 1; dd < 16; dd <<= 1) {
            int n = __shfl_up(wv, dd);
            if (lane >= dd) wv += n;
        }
        if (lane < 16) wsum[lane] = wv - s16;   // exclusive wave base
    }
    __syncthreads();
    if (tid < NBIN) {
        lofs[tid]  = v - c + wsum[wid];
        gbase[tid] = c ? atomicAdd(&bincursor[tid], c) : 0;
    }
    __syncthreads();

    // ---- phase 3: LDS counting-sort scatter ----
#pragma unroll
    for (int k = 0; k < EPT; ++k) {
        if (pk[k] != -1) {
            int bin = ((unsigned)pk[k]) >> 22;
            ebuf[lofs[bin] + rk[k]] = pk[k];
        }
    }
    __syncthreads();

    // ---- phase 4: coalesced per-bin-run writes to part ----
    int total = min(NE - e0, EPT * SCT);
    for (int i = tid; i < total; i += SCT) {
        int e = ebuf[i];
        int bin = ((unsigned)e) >> 22;
        int g = gbase[bin] + (i - lofs[bin]);
        if (g < CAPBIN)
            part[bin * CAPBIN + g] = e & 0x3FFFFF;   // s | local<<16
    }
}

__device__ __forceinline__ f32x2 fp8lo(unsigned u) {
    return __builtin_amdgcn_cvt_pk_f32_fp8((int)u, false);
}
__device__ __forceinline__ f32x2 fp8hi(unsigned u) {
    return __builtin_amdgcn_cvt_pk_f32_fp8((int)u, true);
}

// ---- K2: per-quarter-bin LDS bucket + paired gather-mean over fp8 rows (R2 exact) ----
__global__ __launch_bounds__(256) void k_aggbin(const int* __restrict__ part,
                                                const int* __restrict__ bincursor,
                                                const unsigned* __restrict__ hF8u,
                                                unsigned* __restrict__ hNB2) {
    __shared__ int ldeg[16];
    __shared__ unsigned short bucketL[16 * CAP];   // 2 KB
    int blk = blockIdx.x, tid = threadIdx.x;
    int bin = blk >> 2, sub = blk & 3;
    if (tid < 16) ldeg[tid] = 0;
    __syncthreads();
    int cnt = min(bincursor[bin], CAPBIN);
    const int* pj = part + bin * CAPBIN;
    for (int i = tid; i < cnt; i += 256) {
        int v = pj[i];
        int local = (v >> 16) & 63;
        if ((local >> 4) == sub) {
            int l16 = local & 15;
            int slot = atomicAdd(&ldeg[l16], 1);
            if (slot < CAP) bucketL[l16 * CAP + slot] = (unsigned short)v;
        }
    }
    __syncthreads();
    int wave = tid >> 6, lane = tid & 63;
    int halfid = lane >> 5;        // which edge of the pair
    int l32 = lane & 31;           // feature group: 4 fp8 feats 4*l32..+3
#pragma unroll
    for (int t = 0; t < 4; ++t) {
        int l16 = wave * 4 + t;
        int n = bin * 64 + (sub << 4) + l16;
        if (n >= NN) continue;
        int d = ldeg[l16];
        int c2 = min(d, CAP);
        const unsigned short* bp = &bucketL[l16 * CAP];
        float a0 = 0.f, a1 = 0.f, a2 = 0.f, a3 = 0.f;
        int i = 0;
        for (; i + 16 <= c2; i += 16) {
            unsigned uu[8];
#pragma unroll
            for (int j = 0; j < 8; ++j)
                uu[j] = hF8u[(size_t)bp[i + 2 * j + halfid] * 32 + l32];
#pragma unroll
            for (int j = 0; j < 8; ++j) {
                f32x2 lo = fp8lo(uu[j]);
                f32x2 hi = fp8hi(uu[j]);
                a0 += lo[0]; a1 += lo[1]; a2 += hi[0]; a3 += hi[1];
            }
        }
        for (; i < c2; i += 2) {
            int e = i + halfid;
            unsigned u = 0;
            if (e < c2) u = hF8u[(size_t)bp[e] * 32 + l32];
            f32x2 lo = fp8lo(u);
            f32x2 hi = fp8hi(u);
            a0 += lo[0]; a1 += lo[1]; a2 += hi[0]; a3 += hi[1];
        }
        a0 += __shfl_xor(a0, 32);
        a1 += __shfl_xor(a1, 32);
        a2 += __shfl_xor(a2, 32);
        a3 += __shfl_xor(a3, 32);
        if (halfid == 0) {
            float inv = 1.0f / fmaxf((float)d, 1.0f);
            unsigned p0 = f2bf(a0 * inv) | (f2bf(a1 * inv) << 16);
            unsigned p1 = f2bf(a2 * inv) | (f2bf(a3 * inv) << 16);
            *(uint2*)(hNB2 + (size_t)n * 64 + l32 * 2) = make_uint2(p0, p1);
        }
    }
}

// ---- K3: out = [hB | hNB] @ W^T + b via MFMA, LDS-staged W, j-split (R2 exact) ----
__global__ __launch_bounds__(256) void k_gemm(
    const short* __restrict__ hB, const short* __restrict__ hNB,
    const short* __restrict__ WB, const float* __restrict__ bias,
    float* __restrict__ out)
{
    __shared__ short WL[16384];   // 32 KB
    const int tid = threadIdx.x;
    const int jbase = blockIdx.y * 64;

    for (int g = tid; g < 2048; g += 256) {
        int row = g >> 5;          // 0..63
        int c   = g & 31;          // k-chunk
        int cs  = (c + row) & 31;  // swizzled
        bf16x8 v = *(const bf16x8*)(WB + (size_t)(jbase + row) * 256 + c * 8);
        *(bf16x8*)(&WL[row * 256 + cs * 8]) = v;
    }
    __syncthreads();

    const int wave = tid >> 6;
    const int lane = tid & 63;
    const int q    = lane >> 4;
    const int ln   = lane & 15;
    const int mbase = (blockIdx.x * 4 + wave) * 16;
    int node = mbase + ln;
    if (node >= NN) node = NN - 1;

    f32x4 acc[4];
#pragma unroll
    for (int t = 0; t < 4; ++t) acc[t] = (f32x4){0.f, 0.f, 0.f, 0.f};

#pragma unroll
    for (int k0 = 0; k0 < 8; ++k0) {
        int ck = k0 * 4 + q;
        const short* ap = (k0 < 4) ? (hB  + (size_t)node * 128 + ck * 8)
                                   : (hNB + (size_t)node * 128 + (ck - 16) * 8);
        bf16x8 afr = *(const bf16x8*)ap;
#pragma unroll
        for (int t = 0; t < 4; ++t) {
            int row = t * 16 + ln;
            int cs  = (ck + row) & 31;
            bf16x8 bfr = *(const bf16x8*)(&WL[row * 256 + cs * 8]);
            acc[t] = __builtin_amdgcn_mfma_f32_16x16x32_bf16(afr, bfr, acc[t], 0, 0, 0);
        }
    }

#pragma unroll
    for (int t = 0; t < 4; ++t) {
        float bv = bias[jbase + t * 16 + ln];
#pragma unroll
        for (int r = 0; r < 4; ++r) {
            int m = mbase + q * 4 + r;
            if (m < NN)
                out[(size_t)m * FIN + jbase + t * 16 + ln] = acc[t][r] + bv;
        }
    }
}

extern "C" void kernel_launch(void* const* d_in, const int* in_sizes, int n_in,
                              void* d_out, int out_size, void* d_ws, size_t ws_size,
                              hipStream_t stream) {
    const float* h   = (const float*)d_in[0];
    const int*   src = (const int*)d_in[1];
    const int*   dst = (const int*)d_in[2];
    const float* W   = (const float*)d_in[3];
    const float* b   = (const float*)d_in[4];
    float* out = (float*)d_out;

    int*   wsI = (int*)d_ws;
    short* wsS = (short*)d_ws;

    int* bincursor = wsI + OFF_CUR;
    int* part      = wsI + OFF_PART;
    short* hB      = wsS + S_HB;
    short* hNB     = wsS + S_HNB;
    short* WB      = wsS + S_WB;
    const unsigned* hF8u = (const unsigned*)(wsS + S_HF8);

    hipMemsetAsync(bincursor, 0, NBIN * sizeof(int), stream);
    k_ps     <<<SB + PREPB, SCT, 0, stream>>>(
        h, W, (unsigned*)hB, (unsigned*)WB, (uint2*)(wsS + S_HF8),
        src, dst, bincursor, part);
    k_aggbin <<<NBIN * 4, 256, 0, stream>>>(part, bincursor, hF8u, (unsigned*)hNB);
    k_gemm   <<<dim3((NN + 63) / 64, 2), 256, 0, stream>>>(hB, hNB, WB, b, out);
}